// Round 3
// baseline (586.159 us; speedup 1.0000x reference)
//
#include <hip/hip_runtime.h>
#include <cstdint>
#include <cstddef>

// SummaryAdapter fused kernel for MI355X (gfx950), v3: no hidden LDS tile.
// A-fragments load straight from global f32 hidden; epilogue re-reads hidden
// from global (L2/LLC hit, reuse distance ~us). LDS = 17KB -> 8 blocks/CU.
// L=8 B=2 S=4096 D=2048 N=128 Ds=1024 Da=64.
//
// Workspace layout (bytes):          off      size
//   KF  frag bf16                      0    262144
//   VF  frag bf16                 262144    262144
//   WqF frag bf16                 524288   2097152
//   WoF frag bf16                2621440   2097152
// Requires ws_size >= 4718592.

typedef __attribute__((ext_vector_type(8))) short short8;   // 8 x bf16 (4 VGPR)
typedef __attribute__((ext_vector_type(4))) float f32x4;

#define MFMA16(a, b, c) __builtin_amdgcn_mfma_f32_16x16x32_bf16((a), (b), (c), 0, 0, 0)

__device__ __forceinline__ unsigned short f2bf(float f) {
  unsigned int x = __builtin_bit_cast(unsigned int, f);
  x += 0x7fffu + ((x >> 16) & 1u);        // RNE
  return (unsigned short)(x >> 16);
}
__device__ __forceinline__ short8 cvt8v(f32x4 a, f32x4 b) {
  short8 r;
  r[0] = (short)f2bf(a[0]); r[1] = (short)f2bf(a[1]);
  r[2] = (short)f2bf(a[2]); r[3] = (short)f2bf(a[3]);
  r[4] = (short)f2bf(b[0]); r[5] = (short)f2bf(b[1]);
  r[6] = (short)f2bf(b[2]); r[7] = (short)f2bf(b[3]);
  return r;
}
__device__ __forceinline__ short8 ld_cvt8(const float* p) {
  f32x4 v0 = *(const f32x4*)p, v1 = *(const f32x4*)(p + 4);
  return cvt8v(v0, v1);
}

// ---------------- pre 1: K = bank@Wk^T, V = bank@Wv^T via MFMA -------------
// grid 256 one-wave blocks: bid = l*32 + b*16 + kv*8 + nt. Spreads across CUs.
__global__ __launch_bounds__(64)
void pre_kv_kernel(const float* __restrict__ bank,
                   const float* __restrict__ Wk,
                   const float* __restrict__ Wv,
                   unsigned short* __restrict__ KF, unsigned short* __restrict__ VF) {
  int bid = blockIdx.x;
  int nt = bid & 7, kv = (bid >> 3) & 1, b = (bid >> 4) & 1, l = bid >> 5;
  int lane = threadIdx.x & 63;
  int lo = lane & 15, hi = lane >> 4;
  const float* W  = (kv ? Wv : Wk) + (size_t)l * 65536;
  const float* bk = bank + (size_t)b * 131072;
  int lbq = l * 2 + b;
  f32x4 acc[4];
  #pragma unroll
  for (int at = 0; at < 4; ++at) acc[at] = (f32x4){0.f, 0.f, 0.f, 0.f};
  for (int ks = 0; ks < 32; ++ks) {
    short8 A = ld_cvt8(bk + (nt * 16 + lo) * 1024 + ks * 32 + hi * 8);
    #pragma unroll
    for (int at = 0; at < 4; ++at) {
      short8 B = ld_cvt8(W + (at * 16 + lo) * 1024 + ks * 32 + hi * 8);
      acc[at] = MFMA16(A, B, acc[at]);
    }
  }
  for (int at = 0; at < 4; ++at)
    for (int r = 0; r < 4; ++r) {
      int n = nt * 16 + hi * 4 + r;
      int a = at * 16 + lo;
      unsigned short v = f2bf(acc[at][r]);
      if (kv == 0) {  // KF: n=nt*16+(ln&15), a=ks*32+(ln>>4)*8+j
        int idx = ((lbq * 8 + (n >> 4)) * 2 + (a >> 5)) * 512 +
                  (((a >> 3) & 3) * 16 + (n & 15)) * 8 + (a & 7);
        KF[idx] = v;
      } else {        // VF: a=at*16+(ln&15), n=ks*32+(ln>>4)*8+j
        int idx = ((lbq * 4 + (a >> 4)) * 4 + (n >> 5)) * 512 +
                  (((n >> 3) & 3) * 16 + (a & 15)) * 8 + (n & 7);
        VF[idx] = v;
      }
    }
}

// ---------------- pre 2: Wq/Wo -> bf16 fragment layout ---------------------
__global__ void pre_frag_kernel(const float* __restrict__ Wq, const float* __restrict__ Wo,
                                unsigned short* __restrict__ WqF, unsigned short* __restrict__ WoF) {
  int idx = blockIdx.x * 256 + threadIdx.x;        // 262144 threads
  if (idx < 131072) {
    int t = idx;
    int lane = t & 63, ks = (t >> 6) & 63, at = (t >> 12) & 3, l = t >> 14;
    int a = at * 16 + (lane & 15), d = ks * 32 + (lane >> 4) * 8;
    *(short8*)(WqF + (size_t)t * 8) = ld_cvt8(Wq + ((size_t)(l * 64 + a)) * 2048 + d);
  } else {
    int t = idx - 131072;
    int lane = t & 63, ks = (t >> 6) & 1, dt = (t >> 7) & 127, l = t >> 14;
    int d = dt * 16 + (lane & 15), a = ks * 32 + (lane >> 4) * 8;
    *(short8*)(WoF + (size_t)t * 8) = ld_cvt8(Wo + ((size_t)(l * 2048 + d)) * 64 + a);
  }
}

// ---------------- main fused kernel ----------------------------------------
// grid 4096 = (l:8, b:2, stile:256), 256 threads (4 waves), 17.2 KB static LDS.
// 8 blocks/CU (wave-limited, 100% occupancy target).
__global__ __launch_bounds__(256, 8)
void adapter_main(const float* __restrict__ hidden,
                  const unsigned short* __restrict__ KF, const unsigned short* __restrict__ VF,
                  const unsigned short* __restrict__ WqF, const unsigned short* __restrict__ WoF,
                  const float* __restrict__ gates, float* __restrict__ out) {
  __shared__ float qs[16 * 68];            // Q (scaled), later attn_out
  __shared__ float sc[16 * 132];           // scores
  __shared__ unsigned short pb[16 * 136];  // P bf16, 272 B/row

  // XCD-bijective swizzle (4096 % 8 == 0): one layer per XCD => that XCD's
  // L2 holds only its layer's WqF/WoF/KF/VF fragments.
  int bid0 = blockIdx.x;
  int bid = (bid0 & 7) * 512 + (bid0 >> 3);
  int st = bid & 255, b = (bid >> 8) & 1, l = bid >> 9;
  int s0 = st * 16;
  int tid = threadIdx.x, wave = tid >> 6, lane = tid & 63;
  int lo = lane & 15, hi = lane >> 4;
  size_t hbase = ((size_t)(l * 2 + b) * 4096 + s0) * 2048;
  const float* hsrc = hidden + hbase;
  float gate = 1.0f / (1.0f + __expf(-gates[l]));
  int at = wave;                                 // 0..3 : Da 16-col tile

  // ---- Phase 1: Q = h @ Wq^T, A-fragments straight from global f32 ----
  {
    f32x4 acc = {0.f, 0.f, 0.f, 0.f};
    const float* ap = hsrc + lo * 2048 + hi * 8;
    const unsigned short* wq = WqF + ((size_t)(l * 4 + at) * 64) * 512 + lane * 8;
    #pragma unroll 4
    for (int ks = 0; ks < 64; ++ks) {
      short8 A = ld_cvt8(ap + ks * 32);
      short8 B = *(const short8*)(wq + ks * 512);
      acc = MFMA16(A, B, acc);
    }
    #pragma unroll
    for (int r = 0; r < 4; ++r)                  // fold 1/sqrt(64) into Q
      qs[(hi * 4 + r) * 68 + at * 16 + lo] = acc[r] * 0.125f;
  }
  __syncthreads();                               // B1

  // ---- Phase 2: afrag from Q; scores = Q @ K^T -> sc ----
  {
    short8 afrag[2];
    #pragma unroll
    for (int ks = 0; ks < 2; ++ks) {
      const float* qp = qs + lo * 68 + ks * 32 + hi * 8;
      afrag[ks] = cvt8v(*(const f32x4*)qp, *(const f32x4*)(qp + 4));
    }
    #pragma unroll
    for (int i = 0; i < 2; ++i) {
      int nt = wave * 2 + i;                     // 0..7
      f32x4 acc = {0.f, 0.f, 0.f, 0.f};
      const unsigned short* kf = KF + ((size_t)((l * 2 + b) * 8 + nt) * 2) * 512 + lane * 8;
      acc = MFMA16(afrag[0], *(const short8*)(kf), acc);
      acc = MFMA16(afrag[1], *(const short8*)(kf + 512), acc);
      #pragma unroll
      for (int r = 0; r < 4; ++r)
        sc[(hi * 4 + r) * 132 + nt * 16 + lo] = acc[r];
    }
  }
  __syncthreads();                               // B2

  // ---- Phase 3: softmax over N=128 (16 lanes per row) -> P bf16 ----
  {
    int row = wave * 4 + hi;
    const float* sp = sc + row * 132 + lo * 8;
    f32x4 v0 = *(const f32x4*)sp, v1 = *(const f32x4*)(sp + 4);
    float m = fmaxf(fmaxf(fmaxf(v0[0], v0[1]), fmaxf(v0[2], v0[3])),
                    fmaxf(fmaxf(v1[0], v1[1]), fmaxf(v1[2], v1[3])));
    m = fmaxf(m, __shfl_xor(m, 1)); m = fmaxf(m, __shfl_xor(m, 2));
    m = fmaxf(m, __shfl_xor(m, 4)); m = fmaxf(m, __shfl_xor(m, 8));
    f32x4 e0, e1; float s = 0.f;
    #pragma unroll
    for (int j = 0; j < 4; ++j) { e0[j] = __expf(v0[j] - m); s += e0[j]; }
    #pragma unroll
    for (int j = 0; j < 4; ++j) { e1[j] = __expf(v1[j] - m); s += e1[j]; }
    s += __shfl_xor(s, 1); s += __shfl_xor(s, 2);
    s += __shfl_xor(s, 4); s += __shfl_xor(s, 8);
    float inv = 1.0f / s;
    #pragma unroll
    for (int j = 0; j < 4; ++j) { e0[j] *= inv; e1[j] *= inv; }
    *(short8*)((char*)pb + row * 272 + lo * 16) = cvt8v(e0, e1);
  }
  __syncthreads();                               // B3

  // ---- Phase 4: attn_out = P @ V, result into qs region ----
  {
    f32x4 aoacc = {0.f, 0.f, 0.f, 0.f};
    const unsigned short* vf = VF + ((size_t)((l * 2 + b) * 4 + at) * 4) * 512 + lane * 8;
    #pragma unroll
    for (int ks = 0; ks < 4; ++ks) {
      short8 A = *(const short8*)((const char*)pb + lo * 272 + ks * 64 + hi * 16);
      short8 B = *(const short8*)(vf + ks * 512);
      aoacc = MFMA16(A, B, aoacc);
    }
    #pragma unroll
    for (int r = 0; r < 4; ++r)                  // Q reads finished before B2
      qs[(hi * 4 + r) * 68 + at * 16 + lo] = aoacc[r];
  }
  __syncthreads();                               // B4

  // ---- Phase 5: resid^T = Wo @ attn_out^T; out = hidden + g*resid ----
  {
    short8 bfrag[2];                             // attn_out^T B-fragments
    #pragma unroll
    for (int ks = 0; ks < 2; ++ks) {
      const float* ap2 = qs + lo * 68 + ks * 32 + hi * 8;
      bfrag[ks] = cvt8v(*(const f32x4*)ap2, *(const f32x4*)(ap2 + 4));
    }
    #pragma unroll 2
    for (int i = 0; i < 32; ++i) {
      int dt = wave + i * 4;                     // 0..127 d-tile
      const unsigned short* wo = WoF + ((size_t)(l * 128 + dt) * 2) * 512 + lane * 8;
      short8 A0 = *(const short8*)(wo);
      short8 A1 = *(const short8*)(wo + 512);
      f32x4 acc = {0.f, 0.f, 0.f, 0.f};
      acc = MFMA16(A0, bfrag[0], acc);
      acc = MFMA16(A1, bfrag[1], acc);
      int d0 = dt * 16 + hi * 4;                 // 4 consecutive d
      f32x4 hv = *(const f32x4*)(hsrc + (size_t)lo * 2048 + d0);  // L2/LLC hit
      f32x4 o;
      #pragma unroll
      for (int r = 0; r < 4; ++r) o[r] = hv[r] + gate * acc[r];
      *(f32x4*)(out + hbase + (size_t)lo * 2048 + d0) = o;
    }
  }
}

extern "C" void kernel_launch(void* const* d_in, const int* in_sizes, int n_in,
                              void* d_out, int out_size, void* d_ws, size_t ws_size,
                              hipStream_t stream) {
  const float* hidden = (const float*)d_in[0];
  const float* bank   = (const float*)d_in[1];
  const float* Wq     = (const float*)d_in[2];
  const float* Wk     = (const float*)d_in[3];
  const float* Wv     = (const float*)d_in[4];
  const float* Wo     = (const float*)d_in[5];
  const float* gates  = (const float*)d_in[6];
  float* out = (float*)d_out;

  char* ws = (char*)d_ws;
  unsigned short* KF  = (unsigned short*)(ws);
  unsigned short* VF  = (unsigned short*)(ws + 262144);
  unsigned short* WqF = (unsigned short*)(ws + 524288);
  unsigned short* WoF = (unsigned short*)(ws + 2621440);

  pre_kv_kernel<<<256, 64, 0, stream>>>(bank, Wk, Wv, KF, VF);
  pre_frag_kernel<<<1024, 256, 0, stream>>>(Wq, Wo, WqF, WoF);
  adapter_main<<<4096, 256, 0, stream>>>(hidden, KF, VF, WqF, WoF, gates, out);
}

// Round 4
// 462.109 us; speedup vs baseline: 1.2684x; 1.2684x over previous
//
#include <hip/hip_runtime.h>
#include <cstdint>
#include <cstddef>

// SummaryAdapter fused kernel for MI355X (gfx950), v4: per-wave independent
// tiles, zero block barriers, in-register softmax, 128-VGPR budget.
// L=8 B=2 S=4096 D=2048 N=128 Ds=1024 Da=64.
//
// Workspace layout (bytes):          off      size
//   KF  frag bf16                      0    262144
//   VF  frag bf16                 262144    262144
//   WqF frag bf16                 524288   2097152
//   WoF frag bf16                2621440   2097152
// Requires ws_size >= 4718592.

typedef __attribute__((ext_vector_type(8))) short short8;   // 8 x bf16 (4 VGPR)
typedef __attribute__((ext_vector_type(4))) float f32x4;

#define MFMA16(a, b, c) __builtin_amdgcn_mfma_f32_16x16x32_bf16((a), (b), (c), 0, 0, 0)

__device__ __forceinline__ unsigned short f2bf(float f) {
  unsigned int x = __builtin_bit_cast(unsigned int, f);
  x += 0x7fffu + ((x >> 16) & 1u);        // RNE
  return (unsigned short)(x >> 16);
}
__device__ __forceinline__ short8 cvt8v(f32x4 a, f32x4 b) {
  short8 r;
  r[0] = (short)f2bf(a[0]); r[1] = (short)f2bf(a[1]);
  r[2] = (short)f2bf(a[2]); r[3] = (short)f2bf(a[3]);
  r[4] = (short)f2bf(b[0]); r[5] = (short)f2bf(b[1]);
  r[6] = (short)f2bf(b[2]); r[7] = (short)f2bf(b[3]);
  return r;
}
__device__ __forceinline__ short8 ld_cvt8(const float* p) {
  f32x4 v0 = *(const f32x4*)p, v1 = *(const f32x4*)(p + 4);
  return cvt8v(v0, v1);
}

// ---------------- pre 1: K = bank@Wk^T, V = bank@Wv^T via MFMA -------------
__global__ __launch_bounds__(64)
void pre_kv_kernel(const float* __restrict__ bank,
                   const float* __restrict__ Wk,
                   const float* __restrict__ Wv,
                   unsigned short* __restrict__ KF, unsigned short* __restrict__ VF) {
  int bid = blockIdx.x;
  int nt = bid & 7, kv = (bid >> 3) & 1, b = (bid >> 4) & 1, l = bid >> 5;
  int lane = threadIdx.x & 63;
  int lo = lane & 15, hi = lane >> 4;
  const float* W  = (kv ? Wv : Wk) + (size_t)l * 65536;
  const float* bk = bank + (size_t)b * 131072;
  int lbq = l * 2 + b;
  f32x4 acc[4];
  #pragma unroll
  for (int at = 0; at < 4; ++at) acc[at] = (f32x4){0.f, 0.f, 0.f, 0.f};
  for (int ks = 0; ks < 32; ++ks) {
    short8 A = ld_cvt8(bk + (nt * 16 + lo) * 1024 + ks * 32 + hi * 8);
    #pragma unroll
    for (int at = 0; at < 4; ++at) {
      short8 B = ld_cvt8(W + (at * 16 + lo) * 1024 + ks * 32 + hi * 8);
      acc[at] = MFMA16(A, B, acc[at]);
    }
  }
  for (int at = 0; at < 4; ++at)
    for (int r = 0; r < 4; ++r) {
      int n = nt * 16 + hi * 4 + r;
      int a = at * 16 + lo;
      unsigned short v = f2bf(acc[at][r]);
      if (kv == 0) {
        int idx = ((lbq * 8 + (n >> 4)) * 2 + (a >> 5)) * 512 +
                  (((a >> 3) & 3) * 16 + (n & 15)) * 8 + (a & 7);
        KF[idx] = v;
      } else {
        int idx = ((lbq * 4 + (a >> 4)) * 4 + (n >> 5)) * 512 +
                  (((n >> 3) & 3) * 16 + (a & 15)) * 8 + (n & 7);
        VF[idx] = v;
      }
    }
}

// ---------------- pre 2: Wq/Wo -> bf16 fragment layout ---------------------
__global__ void pre_frag_kernel(const float* __restrict__ Wq, const float* __restrict__ Wo,
                                unsigned short* __restrict__ WqF, unsigned short* __restrict__ WoF) {
  int idx = blockIdx.x * 256 + threadIdx.x;        // 262144 threads
  if (idx < 131072) {
    int t = idx;
    int lane = t & 63, ks = (t >> 6) & 63, at = (t >> 12) & 3, l = t >> 14;
    int a = at * 16 + (lane & 15), d = ks * 32 + (lane >> 4) * 8;
    *(short8*)(WqF + (size_t)t * 8) = ld_cvt8(Wq + ((size_t)(l * 64 + a)) * 2048 + d);
  } else {
    int t = idx - 131072;
    int lane = t & 63, ks = (t >> 6) & 1, dt = (t >> 7) & 127, l = t >> 14;
    int d = dt * 16 + (lane & 15), a = ks * 32 + (lane >> 4) * 8;
    *(short8*)(WoF + (size_t)t * 8) = ld_cvt8(Wo + ((size_t)(l * 2048 + d)) * 64 + a);
  }
}

// ---------------- main fused kernel ----------------------------------------
// grid 1024 x 256 threads. Each WAVE owns one 16-row tile (4096 tiles total,
// all co-resident at 4 blocks/CU). No __syncthreads anywhere.
// Per-wave LDS scratch: 16 rows x 272 B (Q f32[16][68] / P bf16[16][136] /
// attn_out f32[16][68], sequentially reused; intra-wave lgkmcnt ordering).
__global__ __launch_bounds__(256, 4)
void adapter_main(const float* __restrict__ hidden,
                  const unsigned short* __restrict__ KF, const unsigned short* __restrict__ VF,
                  const unsigned short* __restrict__ WqF, const unsigned short* __restrict__ WoF,
                  const float* __restrict__ gates, float* __restrict__ out) {
  __shared__ float scratch[4][16 * 68];            // 4352 B per wave

  // XCD-bijective swizzle (1024 % 8 == 0): XCD x -> blocks [x*128,(x+1)*128)
  // -> tiles [x*512,(x+1)*512) -> exactly layer x. Weights L2-local per XCD.
  int bid0 = blockIdx.x;
  int bid = (bid0 & 7) * 128 + (bid0 >> 3);
  int wave = threadIdx.x >> 6, lane = threadIdx.x & 63;
  int lo = lane & 15, hi = lane >> 4;
  int t = bid * 4 + wave;                          // tile id 0..4095
  int st = t & 255, b = (t >> 8) & 1, l = t >> 9;
  size_t hbase = ((size_t)(l * 2 + b) * 4096 + st * 16) * 2048;
  const float* hsrc = hidden + hbase;
  float gate = 1.0f / (1.0f + __expf(-gates[l]));
  float* qs = scratch[wave];
  unsigned short* qsu = (unsigned short*)qs;
  int lb = l * 2 + b;

  // ---- Phase 1: Q = h @ Wq^T. 4 independent at-chains, A from global f32 ----
  {
    f32x4 qacc[4];
    #pragma unroll
    for (int at = 0; at < 4; ++at) qacc[at] = (f32x4){0.f, 0.f, 0.f, 0.f};
    const float* ap = hsrc + lo * 2048 + hi * 8;
    const unsigned short* wqb = WqF + ((size_t)l * 4 * 64) * 512 + lane * 8;
    #pragma unroll 2
    for (int ks = 0; ks < 64; ++ks) {
      short8 A = ld_cvt8(ap + ks * 32);
      #pragma unroll
      for (int at = 0; at < 4; ++at) {
        short8 B = *(const short8*)(wqb + (size_t)(at * 64 + ks) * 512);
        qacc[at] = MFMA16(A, B, qacc[at]);
      }
    }
    #pragma unroll
    for (int at = 0; at < 4; ++at)
      #pragma unroll
      for (int r = 0; r < 4; ++r)                  // fold 1/sqrt(64) into Q
        qs[(hi * 4 + r) * 68 + at * 16 + lo] = qacc[at][r] * 0.125f;
  }

  // ---- Phase 2: scores = Q @ K^T, all 8 n-tiles in registers ----
  f32x4 sacc[8];
  {
    short8 afrag[2];
    #pragma unroll
    for (int ks = 0; ks < 2; ++ks) {
      const float* qp = qs + lo * 68 + ks * 32 + hi * 8;
      afrag[ks] = cvt8v(*(const f32x4*)qp, *(const f32x4*)(qp + 4));
    }
    const unsigned short* kf = KF + ((size_t)lb * 16) * 512 + lane * 8;
    #pragma unroll
    for (int nt = 0; nt < 8; ++nt) {
      f32x4 a0 = (f32x4){0.f, 0.f, 0.f, 0.f};
      a0 = MFMA16(afrag[0], *(const short8*)(kf + (size_t)nt * 1024), a0);
      sacc[nt] = MFMA16(afrag[1], *(const short8*)(kf + (size_t)nt * 1024 + 512), a0);
    }
  }

  // ---- Phase 3: in-register softmax (row = hi*4+r, cols spread over lo) ----
  {
    #pragma unroll
    for (int r = 0; r < 4; ++r) {
      float m = sacc[0][r];
      #pragma unroll
      for (int nt = 1; nt < 8; ++nt) m = fmaxf(m, sacc[nt][r]);
      m = fmaxf(m, __shfl_xor(m, 1)); m = fmaxf(m, __shfl_xor(m, 2));
      m = fmaxf(m, __shfl_xor(m, 4)); m = fmaxf(m, __shfl_xor(m, 8));
      float s = 0.f;
      #pragma unroll
      for (int nt = 0; nt < 8; ++nt) {
        float e = __expf(sacc[nt][r] - m);
        sacc[nt][r] = e; s += e;
      }
      s += __shfl_xor(s, 1); s += __shfl_xor(s, 2);
      s += __shfl_xor(s, 4); s += __shfl_xor(s, 8);
      float inv = 1.0f / s;
      #pragma unroll
      for (int nt = 0; nt < 8; ++nt) sacc[nt][r] *= inv;
    }
    // scatter P -> scratch as bf16 [16 rows][136 cols], row stride 272 B
    #pragma unroll
    for (int nt = 0; nt < 8; ++nt)
      #pragma unroll
      for (int r = 0; r < 4; ++r)
        qsu[(hi * 4 + r) * 136 + nt * 16 + lo] = f2bf(sacc[nt][r]);
  }

  // ---- Phase 4: attn_out = P @ V (16 MFMAs, 4 independent chains) ----
  {
    short8 pfrag[4];
    #pragma unroll
    for (int ks = 0; ks < 4; ++ks)
      pfrag[ks] = *(const short8*)((const char*)qs + lo * 272 + ks * 64 + hi * 16);
    const unsigned short* vf = VF + ((size_t)lb * 16) * 512 + lane * 8;
    f32x4 ao[4];
    #pragma unroll
    for (int at = 0; at < 4; ++at) {
      f32x4 a = (f32x4){0.f, 0.f, 0.f, 0.f};
      #pragma unroll
      for (int ks = 0; ks < 4; ++ks)
        a = MFMA16(pfrag[ks], *(const short8*)(vf + (size_t)(at * 4 + ks) * 512), a);
      ao[at] = a;
    }
    #pragma unroll
    for (int at = 0; at < 4; ++at)
      #pragma unroll
      for (int r = 0; r < 4; ++r)
        qs[(hi * 4 + r) * 68 + at * 16 + lo] = ao[at][r];
  }

  // ---- Phase 5: resid^T = Wo @ attn_out^T; out = hidden + g*resid ----
  {
    short8 bfrag[2];
    #pragma unroll
    for (int ks = 0; ks < 2; ++ks) {
      const float* ap2 = qs + lo * 68 + ks * 32 + hi * 8;
      bfrag[ks] = cvt8v(*(const f32x4*)ap2, *(const f32x4*)(ap2 + 4));
    }
    const unsigned short* wob = WoF + ((size_t)l * 256) * 512 + lane * 8;
    #pragma unroll 4
    for (int dt = 0; dt < 128; ++dt) {
      short8 A0 = *(const short8*)(wob + (size_t)dt * 1024);
      short8 A1 = *(const short8*)(wob + (size_t)dt * 1024 + 512);
      f32x4 acc = (f32x4){0.f, 0.f, 0.f, 0.f};
      acc = MFMA16(A0, bfrag[0], acc);
      acc = MFMA16(A1, bfrag[1], acc);
      int d0 = dt * 16 + hi * 4;
      f32x4 hv = *(const f32x4*)(hsrc + (size_t)lo * 2048 + d0);
      f32x4 o;
      #pragma unroll
      for (int r = 0; r < 4; ++r) o[r] = hv[r] + gate * acc[r];
      __builtin_nontemporal_store(o, (f32x4*)(out + hbase + (size_t)lo * 2048 + d0));
    }
  }
}

extern "C" void kernel_launch(void* const* d_in, const int* in_sizes, int n_in,
                              void* d_out, int out_size, void* d_ws, size_t ws_size,
                              hipStream_t stream) {
  const float* hidden = (const float*)d_in[0];
  const float* bank   = (const float*)d_in[1];
  const float* Wq     = (const float*)d_in[2];
  const float* Wk     = (const float*)d_in[3];
  const float* Wv     = (const float*)d_in[4];
  const float* Wo     = (const float*)d_in[5];
  const float* gates  = (const float*)d_in[6];
  float* out = (float*)d_out;

  char* ws = (char*)d_ws;
  unsigned short* KF  = (unsigned short*)(ws);
  unsigned short* VF  = (unsigned short*)(ws + 262144);
  unsigned short* WqF = (unsigned short*)(ws + 524288);
  unsigned short* WoF = (unsigned short*)(ws + 2621440);

  pre_kv_kernel<<<256, 64, 0, stream>>>(bank, Wk, Wv, KF, VF);
  pre_frag_kernel<<<1024, 256, 0, stream>>>(Wq, Wo, WqF, WoF);
  adapter_main<<<1024, 256, 0, stream>>>(hidden, KF, VF, WqF, WoF, gates, out);
}